// Round 17
// baseline (1689.552 us; speedup 1.0000x reference)
//
#include <hip/hip_runtime.h>
#include <math.h>

typedef unsigned long long u64;
typedef unsigned int u32;
typedef unsigned short u16;
typedef __attribute__((ext_vector_type(8))) short bf16x8;
typedef __attribute__((ext_vector_type(4))) float f32x4;

#define D   256
#define ECH 16          // edges per thread
#define EBLK (256*ECH)  // edges per block
#define BAND_W 2048     // rank window half-width around k for f64 refinement
#define BAND_DELTA 1e-3f
#define HR  50176       // histogram nodes per range (12544 u32 words, u8-packed, 50KB LDS)
#define HCH 64          // edge chunks (blocks per range)
#define NBUCK 65536

__device__ __forceinline__ double lrelu(double v){ return v > 0.0 ? v : 0.2*v; }
__device__ __forceinline__ float  lreluf(float v){ return v > 0.0f ? v : 0.2f*v; }

__device__ __forceinline__ u16 f2bf(float f){
  union{float f; u32 u;} v; v.f = f;
  u32 r = v.u + 0x7FFFu + ((v.u >> 16) & 1u);   // RNE
  return (u16)(r >> 16);
}
__device__ __forceinline__ float bf2f(u16 b){
  union{u32 u; float f;} v; v.u = ((u32)b) << 16; return v.f;
}

// ---------------- degree: partitioned LDS histogram, packed u8 counters -------------
// 2 blocks/CU (50KB LDS) for latency hiding; per-(chunk,node) counts max ~8 << 255.
__global__ __launch_bounds__(256) void k_deghist(const int* __restrict__ row, int E,
                                                 u32* __restrict__ partial, int NR){
  __shared__ u32 h[HR/4];
  const int tid = threadIdx.x;
  const int r = blockIdx.x % NR;
  const int c = blockIdx.x / NR;
  for (int i = tid; i < HR/4; i += 256) h[i] = 0;
  __syncthreads();
  const int lo = r * HR;
  int CE = ((E + HCH - 1) / HCH + 3) & ~3;      // chunk size, multiple of 4
  const int e0 = c * CE;
  const int e1 = min(e0 + CE, E);
  for (int e = e0 + tid*4; e < e1; e += 256*4){
    if (e + 3 < e1){
      int4 v = *(const int4*)(row + e);
      u32 d0 = (u32)(v.x - lo), d1 = (u32)(v.y - lo);
      u32 d2 = (u32)(v.z - lo), d3 = (u32)(v.w - lo);
      if (d0 < (u32)HR) atomicAdd(&h[d0 >> 2], 1u << ((d0 & 3)*8));
      if (d1 < (u32)HR) atomicAdd(&h[d1 >> 2], 1u << ((d1 & 3)*8));
      if (d2 < (u32)HR) atomicAdd(&h[d2 >> 2], 1u << ((d2 & 3)*8));
      if (d3 < (u32)HR) atomicAdd(&h[d3 >> 2], 1u << ((d3 & 3)*8));
    } else {
      for (int j = 0; j < 4 && e + j < e1; ++j){
        u32 d = (u32)(row[e+j] - lo);
        if (d < (u32)HR) atomicAdd(&h[d >> 2], 1u << ((d & 3)*8));
      }
    }
  }
  __syncthreads();
  u32* plane = partial + (size_t)blockIdx.x * (HR/4);
  for (int i = tid; i < HR/4; i += 256) plane[i] = h[i];
}

__global__ void k_degred2(const u32* __restrict__ partial, int N, int NR,
                          int* __restrict__ deg, u64* __restrict__ out){
  __shared__ u64 sh[256];
  u64 local = 0;
  int stride = gridDim.x*blockDim.x;
  for (int i = blockIdx.x*blockDim.x + threadIdx.x; i < N; i += stride){
    int r = i / HR, off = i % HR;
    const int word = off >> 2, shift = (off & 3)*8;
    u32 s = 0;
    #pragma unroll 8
    for (int c = 0; c < HCH; ++c)
      s += (partial[(size_t)(c*NR + r)*(HR/4) + word] >> shift) & 0xFFu;
    deg[i] = (int)s;
    local += (u64)s * (u64)s;
  }
  sh[threadIdx.x] = local; __syncthreads();
  for (int s = 128; s > 0; s >>= 1){
    if (threadIdx.x < s) sh[threadIdx.x] += sh[threadIdx.x+s];
    __syncthreads();
  }
  if (threadIdx.x == 0) atomicAdd(out, sh[0]);
}

// ---------------- fused prep + weight pre-swizzle ----------------
__global__ void k_prep_wsw(const float* __restrict__ wS1, const float* __restrict__ wF1,
                           const float* __restrict__ wP,
                           const float* __restrict__ alpha, const float* __restrict__ beta,
                           const u64* __restrict__ sumsq,
                           u16* __restrict__ wswH, u16* __restrict__ wswL,
                           u16* __restrict__ wPH,
                           double* __restrict__ s1b, double* __restrict__ scal,
                           float* __restrict__ s1bf, float* __restrict__ scalf){
  const int b = blockIdx.x;
  if (b < 384){
    int idx = b*256 + threadIdx.x;              // 24*8*64*8 = 98304
    int i    = idx & 7;
    int lane = (idx >> 3) & 63;
    int sg   = (idx >> 9) & 7;
    int t    = idx >> 12;
    int k = sg*32 + ((lane >> 4) & 3)*8 + i;
    int c16 = lane & 15;
    float wv;
    if (t < 16) wv = wS1[k*256 + t*16 + c16];
    else        wv = wF1[k*128 + (t-16)*16 + c16];
    u16 h = f2bf(wv);
    wswH[idx] = h;
    wswL[idx] = f2bf(wv - bf2f(h));
  } else if (b < 640){
    int idx = (b-384)*256 + threadIdx.x;        // 16*8*64*8 = 65536
    int i    = idx & 7;
    int lane = (idx >> 3) & 63;
    int sg   = (idx >> 9) & 7;
    int t    = idx >> 12;
    int k = sg*32 + ((lane >> 4) & 3)*8 + i;
    wPH[idx] = f2bf(wP[k*256 + t*16 + (lane & 15)]);
  } else {
    int j = threadIdx.x;
    double s = 0.0;
    for (int r = 0; r < D; ++r) s += (double)wS1[(D + r)*D + j];
    s1b[j] = s;
    s1bf[j] = (float)s;
    if (j == 0){
      double a = 1.0/(1.0 + exp(-(double)alpha[0]));
      double bb = 1.0/(1.0 + exp(-(double)beta[0]));
      scal[0] = a/(a+bb);
      scal[1] = bb/(a+bb);
      double dn = sqrt((double)(*sumsq));
      scal[2] = dn > 1e-12 ? dn : 1e-12;
      scalf[0] = (float)scal[0];
      scalf[1] = (float)scal[1];
      scalf[2] = (float)(1.0/scal[2]);
    }
  }
}

// ---------------- scores via split-bf16 MFMA (8 waves/EU hint, lean epilogue) -------
__global__ __launch_bounds__(512, 8) void k_scores_mfma(
    const float* __restrict__ x, const int* __restrict__ deg,
    const u16* __restrict__ wswH, const u16* __restrict__ wswL,
    const float* __restrict__ bS1, const float* __restrict__ wS2, const float* __restrict__ bS2,
    const float* __restrict__ bF1, const float* __restrict__ wF2, const float* __restrict__ bF2,
    const float* __restrict__ s1bf, const float* __restrict__ scalf,
    float* __restrict__ s32, u64* __restrict__ keysrc, u32* __restrict__ kmm, int N)
{
  __shared__ u16 xsh[2][4096];
  __shared__ u16 xsl[2][4096];
  __shared__ float dnsh[64];
  __shared__ float part_s[64][9];
  __shared__ float part_f[64][9];

  const int tid  = threadIdx.x;
  const int lane = tid & 63;
  const int w    = tid >> 6;
  const int node0 = blockIdx.x * 64;

  if (tid < 64){
    int node = node0 + tid;
    dnsh[tid] = (node < N) ? ((float)deg[node] * scalf[2]) : 0.0f;
  }

  const int row_st = tid >> 3;
  const int seg_st = tid & 7;
  const int unit_w = row_st*8 + (seg_st ^ (row_st & 7));
  const float* srcbase = x + (size_t)(node0 + row_st)*D + seg_st*8;
  const bool rv = (node0 + row_st) < N;

  f32x4 acc[4][3];
  #pragma unroll
  for (int m = 0; m < 4; ++m)
    #pragma unroll
    for (int n = 0; n < 3; ++n) acc[m][n] = (f32x4){0.f,0.f,0.f,0.f};

  float xr[8];
  {
    if (rv){
      float4 a = *(const float4*)(srcbase);
      float4 b = *(const float4*)(srcbase + 4);
      xr[0]=a.x; xr[1]=a.y; xr[2]=a.z; xr[3]=a.w;
      xr[4]=b.x; xr[5]=b.y; xr[6]=b.z; xr[7]=b.w;
    } else {
      #pragma unroll
      for (int i = 0; i < 8; ++i) xr[i] = 0.f;
    }
  }

  #pragma unroll
  for (int c = 0; c < 4; ++c){
    const int pb = c & 1;
    {
      u16 h[8];
      #pragma unroll
      for (int i = 0; i < 8; ++i) h[i] = f2bf(xr[i]);
      uint4 H; H.x = (u32)h[0] | ((u32)h[1]<<16); H.y = (u32)h[2] | ((u32)h[3]<<16);
               H.z = (u32)h[4] | ((u32)h[5]<<16); H.w = (u32)h[6] | ((u32)h[7]<<16);
      u16 l[8];
      #pragma unroll
      for (int i = 0; i < 8; ++i) l[i] = f2bf(xr[i] - bf2f(h[i]));
      uint4 L; L.x = (u32)l[0] | ((u32)l[1]<<16); L.y = (u32)l[2] | ((u32)l[3]<<16);
               L.z = (u32)l[4] | ((u32)l[5]<<16); L.w = (u32)l[6] | ((u32)l[7]<<16);
      *(uint4*)&xsh[pb][unit_w*8] = H;
      *(uint4*)&xsl[pb][unit_w*8] = L;
    }
    __syncthreads();
    if (c < 3){
      const float* sn = srcbase + (c+1)*64;
      if (rv){
        float4 a = *(const float4*)(sn);
        float4 b = *(const float4*)(sn + 4);
        xr[0]=a.x; xr[1]=a.y; xr[2]=a.z; xr[3]=a.w;
        xr[4]=b.x; xr[5]=b.y; xr[6]=b.z; xr[7]=b.w;
      }
    }
    #pragma unroll
    for (int s = 0; s < 2; ++s){
      const int sg = c*2 + s;
      bf16x8 ah[4], al[4];
      #pragma unroll
      for (int mt = 0; mt < 4; ++mt){
        int row = mt*16 + (lane & 15);
        int seg = s*4 + (lane >> 4);
        int un  = row*8 + (seg ^ (row & 7));
        ah[mt] = *(const bf16x8*)&xsh[pb][un*8];
        al[mt] = *(const bf16x8*)&xsl[pb][un*8];
      }
      const int t0 = w*3;
      size_t o0 = ((size_t)(t0*8 + sg)*64 + lane)*8;
      bf16x8 bh = *(const bf16x8*)&wswH[o0];
      bf16x8 bl = *(const bf16x8*)&wswL[o0];
      #pragma unroll
      for (int nt = 0; nt < 3; ++nt){
        bf16x8 nbh = bh, nbl = bl;
        if (nt < 2){
          size_t on = ((size_t)((t0+nt+1)*8 + sg)*64 + lane)*8;
          nbh = *(const bf16x8*)&wswH[on];
          nbl = *(const bf16x8*)&wswL[on];
        }
        #pragma unroll
        for (int mt = 0; mt < 4; ++mt){
          acc[mt][nt] = __builtin_amdgcn_mfma_f32_16x16x32_bf16(ah[mt], bh, acc[mt][nt], 0,0,0);
          acc[mt][nt] = __builtin_amdgcn_mfma_f32_16x16x32_bf16(al[mt], bh, acc[mt][nt], 0,0,0);
          acc[mt][nt] = __builtin_amdgcn_mfma_f32_16x16x32_bf16(ah[mt], bl, acc[mt][nt], 0,0,0);
        }
        bh = nbh; bl = nbl;
      }
    }
    if (c < 3) __syncthreads();
  }

  // epilogue: accumulate over nt first, then one 16-lane shuffle reduction per array
  const int c16 = lane & 15;
  float dnl[4][4];
  #pragma unroll
  for (int mt = 0; mt < 4; ++mt)
    #pragma unroll
    for (int j = 0; j < 4; ++j)
      dnl[mt][j] = dnsh[mt*16 + (lane>>4)*4 + j];

  float psv[4][4], pfv[4][4];
  #pragma unroll
  for (int mt = 0; mt < 4; ++mt)
    #pragma unroll
    for (int j = 0; j < 4; ++j){ psv[mt][j] = 0.f; pfv[mt][j] = 0.f; }

  #pragma unroll
  for (int nt = 0; nt < 3; ++nt){
    const int t = w*3 + nt;
    const bool isS = (t < 16);
    const int col = isS ? t*16 + c16 : (t-16)*16 + c16;
    const float bias = isS ? bS1[col] : bF1[col];
    const float sbv  = isS ? s1bf[col] : 0.f;
    const float vv   = isS ? wS2[col] : wF2[col];
    #pragma unroll
    for (int mt = 0; mt < 4; ++mt){
      #pragma unroll
      for (int j = 0; j < 4; ++j){
        float v = acc[mt][nt][j] + bias + dnl[mt][j]*sbv;
        v = lreluf(v) * vv;
        if (isS) psv[mt][j] += v; else pfv[mt][j] += v;
      }
    }
  }
  #pragma unroll
  for (int mt = 0; mt < 4; ++mt){
    #pragma unroll
    for (int j = 0; j < 4; ++j){
      float a = psv[mt][j], b = pfv[mt][j];
      a += __shfl_xor(a, 1); b += __shfl_xor(b, 1);
      a += __shfl_xor(a, 2); b += __shfl_xor(b, 2);
      a += __shfl_xor(a, 4); b += __shfl_xor(b, 4);
      a += __shfl_xor(a, 8); b += __shfl_xor(b, 8);
      if (c16 == 0){
        int row = mt*16 + (lane>>4)*4 + j;
        part_s[row][w] = a;
        part_f[row][w] = b;
      }
    }
  }
  __syncthreads();
  if (tid < 64){
    int node = node0 + tid;
    u32 key32mn = 0xFFFFFFFFu, key32mx = 0u;
    if (node < N){
      float sv = 0.f, fv = 0.f;
      #pragma unroll
      for (int ww = 0; ww < 8; ++ww){ sv += part_s[tid][ww]; fv += part_f[tid][ww]; }
      float sc = scalf[0]*(sv + bS2[0]) + scalf[1]*(fv + bF2[0]);
      s32[node] = sc;
      u32 bits = __float_as_uint(sc);
      u32 ord = (bits >> 31) ? ~bits : (bits | 0x80000000u);
      u32 key32 = ~ord;
      keysrc[node] = ((u64)key32 << 32) | (u32)node;
      key32mn = key32; key32mx = key32;
    }
    #pragma unroll
    for (int off = 32; off > 0; off >>= 1){
      u32 on = __shfl_xor(key32mn, off);
      u32 ox = __shfl_xor(key32mx, off);
      key32mn = min(key32mn, on);
      key32mx = max(key32mx, ox);
    }
    if (tid == 0){
      atomicMin(&kmm[0], key32mn);
      atomicMax(&kmm[1], key32mx);
    }
  }
}

// ---------------- counting sort: hist -> scan -> scatter ----------------
__global__ void k_hist(const u64* __restrict__ keysrc, int N,
                       const u32* __restrict__ kmm, u32* __restrict__ hist){
  const u32 kmin = kmm[0];
  const u64 rng = (u64)(kmm[1] - kmm[0]) + 1;
  int stride = gridDim.x*blockDim.x;
  for (int i = blockIdx.x*blockDim.x + threadIdx.x; i < N; i += stride){
    u32 key = (u32)(keysrc[i] >> 32);
    u32 b = (u32)((((u64)(key - kmin)) << 16) / rng);
    atomicAdd(&hist[b], 1u);
  }
}

__global__ __launch_bounds__(1024) void k_scan64k(const u32* __restrict__ hist,
                                                  u32* __restrict__ boff){
  __shared__ u32 ts[1024];
  const int t = threadIdx.x;
  u32 loc[64];
  u32 s = 0;
  const uint4* hp = (const uint4*)(hist + t*64);
  #pragma unroll
  for (int i = 0; i < 16; ++i){
    uint4 v = hp[i];
    loc[i*4+0]=v.x; loc[i*4+1]=v.y; loc[i*4+2]=v.z; loc[i*4+3]=v.w;
    s += v.x + v.y + v.z + v.w;
  }
  ts[t] = s; __syncthreads();
  for (int d = 1; d < 1024; d <<= 1){
    u32 v = (t >= d) ? ts[t-d] : 0;
    __syncthreads();
    ts[t] += v;
    __syncthreads();
  }
  u32 run = ts[t] - s;
  u32* bp = boff + t*64;
  #pragma unroll 8
  for (int i = 0; i < 64; ++i){ bp[i] = run; run += loc[i]; }
}

__global__ void k_scatter(const u64* __restrict__ keysrc, int N,
                          const u32* __restrict__ kmm, u32* __restrict__ boff,
                          u64* __restrict__ keyS){
  const u32 kmin = kmm[0];
  const u64 rng = (u64)(kmm[1] - kmm[0]) + 1;
  int stride = gridDim.x*blockDim.x;
  for (int i = blockIdx.x*blockDim.x + threadIdx.x; i < N; i += stride){
    u64 kv = keysrc[i];
    u32 key = (u32)(kv >> 32);
    u32 b = (u32)((((u64)(key - kmin)) << 16) / rng);
    u32 pos = atomicAdd(&boff[b], 1u);
    keyS[pos] = kv;
  }
}

// ---------------- f64 band refinement around rank-k cutoff (cut fused in) -----------
__global__ __launch_bounds__(256) void kr_rescore(
    const u64* __restrict__ keys, const float* __restrict__ s32,
    const float* __restrict__ x, const int* __restrict__ deg,
    const float* __restrict__ wS1, const float* __restrict__ bS1,
    const float* __restrict__ wS2, const float* __restrict__ bS2,
    const float* __restrict__ wF1, const float* __restrict__ bF1,
    const float* __restrict__ wF2, const float* __restrict__ bF2,
    const double* __restrict__ s1b, const double* __restrict__ scal,
    u32* __restrict__ r01, double* __restrict__ bandS, int k, int N)
{
  const int r = k - BAND_W + blockIdx.x;
  if (r < 0 || r >= N) return;
  u32 kk32 = (u32)(keys[k-1] >> 32);
  u32 kord = ~kk32;
  u32 ku = (kord & 0x80000000u) ? (kord ^ 0x80000000u) : ~kord;
  const float ccut = __uint_as_float(ku);
  const int node = (int)(u32)(keys[r] & 0xFFFFFFFFULL);
  const float s = s32[node];
  if (s < ccut - BAND_DELTA || s > ccut + BAND_DELTA){
    if (threadIdx.x == 0) bandS[blockIdx.x] = (double)s;
    return;
  }

  const int tid = threadIdx.x;
  if (tid == 0){ atomicMin(&r01[0], (u32)r); atomicMax(&r01[1], (u32)r); }

  __shared__ float xr[256];
  __shared__ double rsp[4], rfp[4];
  xr[tid] = x[(size_t)node*D + tid];
  __syncthreads();

  const int j = tid;
  double a0=0.0, a1=0.0, a2=0.0, a3=0.0;
  double b0=0.0, b1=0.0, b2=0.0, b3=0.0;
  if (j < 128){
    for (int rr = 0; rr < D; rr += 4){
      double x0 = (double)xr[rr+0], x1 = (double)xr[rr+1];
      double x2 = (double)xr[rr+2], x3 = (double)xr[rr+3];
      a0 = fma(x0, (double)wS1[(rr+0)*D + j], a0);
      a1 = fma(x1, (double)wS1[(rr+1)*D + j], a1);
      a2 = fma(x2, (double)wS1[(rr+2)*D + j], a2);
      a3 = fma(x3, (double)wS1[(rr+3)*D + j], a3);
      b0 = fma(x0, (double)wF1[(rr+0)*128 + j], b0);
      b1 = fma(x1, (double)wF1[(rr+1)*128 + j], b1);
      b2 = fma(x2, (double)wF1[(rr+2)*128 + j], b2);
      b3 = fma(x3, (double)wF1[(rr+3)*128 + j], b3);
    }
  } else {
    for (int rr = 0; rr < D; rr += 4){
      double x0 = (double)xr[rr+0], x1 = (double)xr[rr+1];
      double x2 = (double)xr[rr+2], x3 = (double)xr[rr+3];
      a0 = fma(x0, (double)wS1[(rr+0)*D + j], a0);
      a1 = fma(x1, (double)wS1[(rr+1)*D + j], a1);
      a2 = fma(x2, (double)wS1[(rr+2)*D + j], a2);
      a3 = fma(x3, (double)wS1[(rr+3)*D + j], a3);
    }
  }
  double accA = ((a0+a1)+(a2+a3)) + (double)bS1[j] + ((double)deg[node]/scal[2]) * s1b[j];
  double sp = lrelu(accA) * (double)wS2[j];
  double fp = 0.0;
  if (j < 128){
    double accB = ((b0+b1)+(b2+b3)) + (double)bF1[j];
    fp = lrelu(accB) * (double)wF2[j];
  }

  const int lane = tid & 63, wave = tid >> 6;
  #pragma unroll
  for (int off = 32; off > 0; off >>= 1){
    sp += __shfl_down(sp, off);
    fp += __shfl_down(fp, off);
  }
  if (lane == 0){ rsp[wave] = sp; rfp[wave] = fp; }
  __syncthreads();
  if (tid == 0){
    double SP = rsp[0]+rsp[1]+rsp[2]+rsp[3];
    double FP = rfp[0]+rfp[1]+rfp[2]+rfp[3];
    bandS[blockIdx.x] = scal[0]*(SP + (double)bS2[0]) + scal[1]*(FP + (double)bF2[0]);
  }
}

__global__ __launch_bounds__(1024) void kr_bandsort(u64* __restrict__ keys,
    const double* __restrict__ bandS, const u32* __restrict__ r01, int k){
  __shared__ double bs[4096];
  __shared__ int bi[4096];
  if (r01[0] == 0xFFFFFFFFu) return;     // empty band
  const int r0 = (int)r01[0], r1 = (int)r01[1];
  int nb = r1 - r0 + 1;
  if (nb <= 1) return;
  if (nb > 4096) nb = 4096;
  int M = 1; while (M < nb) M <<= 1;
  const int tid = threadIdx.x;
  const int sbase = r0 - (k - BAND_W);
  for (int m = tid; m < M; m += 1024){
    if (m < nb){ bs[m] = bandS[sbase + m]; bi[m] = (int)(u32)(keys[r0+m] & 0xFFFFFFFFULL); }
    else       { bs[m] = -1.0/0.0;         bi[m] = 0x7FFFFFFF; }
  }
  __syncthreads();
  for (int size = 2; size <= M; size <<= 1){
    for (int stride = size >> 1; stride > 0; stride >>= 1){
      for (int p = tid; p < (M >> 1); p += 1024){
        int i = 2*p - (p & (stride-1));
        int jj = i + stride;
        bool up = ((i & size) == 0);
        double si_ = bs[i], sj = bs[jj];
        int ii = bi[i], ij = bi[jj];
        bool gt = (si_ < sj) || (si_ == sj && ii > ij);
        if (gt == up){ bs[i]=sj; bs[jj]=si_; bi[i]=ij; bi[jj]=ii; }
      }
      __syncthreads();
    }
  }
  for (int m = tid; m < nb; m += 1024)
    keys[r0+m] = (u64)(u32)bi[m];
}

// ---------------- x_pooled via pure-bf16 MFMA (finalize fused, 8 waves/EU hint) -----
__global__ __launch_bounds__(512, 8) void k_xpool_mfma(
    const float* __restrict__ x, const u64* __restrict__ keys,
    const u16* __restrict__ wH, const float* __restrict__ bP,
    const float* __restrict__ s32, int* __restrict__ nmap, float* __restrict__ outS,
    float* __restrict__ out, int kk)
{
  __shared__ u16 xsh[2][4096];

  const int tid  = threadIdx.x;
  const int lane = tid & 63;
  const int w    = tid >> 6;
  const int p0 = blockIdx.x * 64;
  if (p0 >= kk) return;

  // fused k_finalize for this block's 64 ranks
  if (tid < 64){
    int p = p0 + tid;
    if (p < kk){
      int nd = (int)(u32)(keys[p] & 0xFFFFFFFFULL);
      nmap[nd] = p;
      outS[p] = s32[nd];
    }
  }

  const int row_st = tid >> 3;
  const int seg_st = tid & 7;
  const int unit_w = row_st*8 + (seg_st ^ (row_st & 7));
  int prow = p0 + row_st; if (prow >= kk) prow = kk - 1;
  const int node = (int)(u32)(keys[prow] & 0xFFFFFFFFULL);
  const float* srcbase = x + (size_t)node*D + seg_st*8;

  f32x4 acc[4][2];
  #pragma unroll
  for (int m = 0; m < 4; ++m){ acc[m][0] = (f32x4){0.f,0.f,0.f,0.f}; acc[m][1] = (f32x4){0.f,0.f,0.f,0.f}; }

  float xr[8];
  {
    float4 a = *(const float4*)(srcbase);
    float4 b = *(const float4*)(srcbase + 4);
    xr[0]=a.x; xr[1]=a.y; xr[2]=a.z; xr[3]=a.w;
    xr[4]=b.x; xr[5]=b.y; xr[6]=b.z; xr[7]=b.w;
  }

  #pragma unroll
  for (int c = 0; c < 4; ++c){
    const int pb = c & 1;
    {
      u16 h[8];
      #pragma unroll
      for (int i = 0; i < 8; ++i) h[i] = f2bf(xr[i]);
      uint4 H; H.x = (u32)h[0] | ((u32)h[1]<<16); H.y = (u32)h[2] | ((u32)h[3]<<16);
               H.z = (u32)h[4] | ((u32)h[5]<<16); H.w = (u32)h[6] | ((u32)h[7]<<16);
      *(uint4*)&xsh[pb][unit_w*8] = H;
    }
    __syncthreads();
    if (c < 3){
      const float* sn = srcbase + (c+1)*64;
      float4 a = *(const float4*)(sn);
      float4 b = *(const float4*)(sn + 4);
      xr[0]=a.x; xr[1]=a.y; xr[2]=a.z; xr[3]=a.w;
      xr[4]=b.x; xr[5]=b.y; xr[6]=b.z; xr[7]=b.w;
    }
    #pragma unroll
    for (int s = 0; s < 2; ++s){
      const int sg = c*2 + s;
      bf16x8 ah[4];
      #pragma unroll
      for (int mt = 0; mt < 4; ++mt){
        int row = mt*16 + (lane & 15);
        int seg = s*4 + (lane >> 4);
        int un  = row*8 + (seg ^ (row & 7));
        ah[mt] = *(const bf16x8*)&xsh[pb][un*8];
      }
      const int t0 = w*2;
      size_t o0 = ((size_t)(t0*8 + sg)*64 + lane)*8;
      bf16x8 bh = *(const bf16x8*)&wH[o0];
      #pragma unroll
      for (int nt = 0; nt < 2; ++nt){
        bf16x8 nbh = bh;
        if (nt < 1){
          size_t on = ((size_t)((t0+1)*8 + sg)*64 + lane)*8;
          nbh = *(const bf16x8*)&wH[on];
        }
        #pragma unroll
        for (int mt = 0; mt < 4; ++mt)
          acc[mt][nt] = __builtin_amdgcn_mfma_f32_16x16x32_bf16(ah[mt], bh, acc[mt][nt], 0,0,0);
        bh = nbh;
      }
    }
    if (c < 3) __syncthreads();
  }

  const int c16 = lane & 15, r4 = (lane >> 4)*4;
  #pragma unroll
  for (int nt = 0; nt < 2; ++nt){
    const int col = (w*2 + nt)*16 + c16;
    const float bias = bP[col];
    #pragma unroll
    for (int mt = 0; mt < 4; ++mt){
      #pragma unroll
      for (int j = 0; j < 4; ++j){
        int p = p0 + mt*16 + r4 + j;
        if (p < kk) out[(size_t)p*D + col] = lreluf(acc[mt][nt][j] + bias);
      }
    }
  }
}

// ---------------- edge remap + stable compaction (r13-proven 3-kernel) --------------
__global__ __launch_bounds__(256) void k_ecount(const int* __restrict__ erow, const int* __restrict__ ecol,
    const int* __restrict__ nmap, int E, int* __restrict__ bcount){
  __shared__ int sc[256];
  const int tid = threadIdx.x;
  const int base = blockIdx.x*EBLK + tid*ECH;
  int cnt = 0;
  #pragma unroll
  for (int q = 0; q < ECH; ++q){
    int e = base + q;
    if (e < E){
      if (nmap[erow[e]] >= 0 && nmap[ecol[e]] >= 0) cnt++;
    }
  }
  sc[tid] = cnt; __syncthreads();
  for (int s = 128; s > 0; s >>= 1){
    if (tid < s) sc[tid] += sc[tid+s];
    __syncthreads();
  }
  if (tid == 0) bcount[blockIdx.x] = sc[0];
}

__global__ __launch_bounds__(1024) void k_escan(const int* __restrict__ bcount, int nblk,
                                                int* __restrict__ boff, int* __restrict__ tot){
  __shared__ int sh[1024];
  const int tid = threadIdx.x;
  int carry = 0;
  for (int s = 0; s < nblk; s += 1024){
    int v = (s + tid < nblk) ? bcount[s+tid] : 0;
    sh[tid] = v; __syncthreads();
    for (int d = 1; d < 1024; d <<= 1){
      int t = (tid >= d) ? sh[tid-d] : 0;
      __syncthreads();
      sh[tid] += t;
      __syncthreads();
    }
    if (s + tid < nblk) boff[s+tid] = carry + sh[tid] - v;
    carry += sh[1023];
    __syncthreads();
  }
  if (tid == 0) *tot = carry;
}

__global__ void k_efill_tail(float* __restrict__ outR, float* __restrict__ outC,
                             const int* __restrict__ tot, int E){
  const int t0 = *tot;
  int stride = gridDim.x*blockDim.x;
  for (int i = t0 + blockIdx.x*blockDim.x + threadIdx.x; i < E; i += stride){
    outR[i] = -1.0f;
    outC[i] = -1.0f;
  }
}

__global__ __launch_bounds__(256) void k_escatter(const int* __restrict__ erow, const int* __restrict__ ecol,
    const int* __restrict__ nmap, int E, const int* __restrict__ boff,
    float* __restrict__ outR, float* __restrict__ outC){
  __shared__ int sc[256];
  const int tid = threadIdx.x;
  const int base = blockIdx.x*EBLK + tid*ECH;
  int mr[ECH], mc[ECH];
  int cnt = 0;
  #pragma unroll
  for (int q = 0; q < ECH; ++q){
    int e = base + q;
    int a = -1, b = -1;
    if (e < E){ a = nmap[erow[e]]; b = nmap[ecol[e]]; }
    mr[q] = a; mc[q] = b;
    if (a >= 0 && b >= 0) cnt++;
  }
  sc[tid] = cnt; __syncthreads();
  int v = cnt;
  for (int d = 1; d < 256; d <<= 1){
    int t = (tid >= d) ? sc[tid-d] : 0;
    __syncthreads();
    sc[tid] += t;
    __syncthreads();
  }
  int pos = boff[blockIdx.x] + sc[tid] - v;
  #pragma unroll
  for (int q = 0; q < ECH; ++q){
    if (mr[q] >= 0 && mc[q] >= 0){
      outR[pos] = (float)mr[q];
      outC[pos] = (float)mc[q];
      pos++;
    }
  }
}

// ---------------- host ----------------
extern "C" void kernel_launch(void* const* d_in, const int* in_sizes, int n_in,
                              void* d_out, int out_size, void* d_ws, size_t ws_size,
                              hipStream_t stream)
{
  const float* x   = (const float*)d_in[0];
  const int*   ei  = (const int*)d_in[1];
  const float* wS1 = (const float*)d_in[2];
  const float* bS1 = (const float*)d_in[3];
  const float* wS2 = (const float*)d_in[4];
  const float* bS2 = (const float*)d_in[5];
  const float* wF1 = (const float*)d_in[6];
  const float* bF1 = (const float*)d_in[7];
  const float* wF2 = (const float*)d_in[8];
  const float* bF2 = (const float*)d_in[9];
  const float* wP  = (const float*)d_in[10];
  const float* bP  = (const float*)d_in[11];
  const float* alpha = (const float*)d_in[12];
  const float* beta  = (const float*)d_in[13];
  (void)n_in; (void)out_size; (void)ws_size;

  const int N = in_sizes[0] / D;
  const int E = in_sizes[1] / 2;
  int k = (int)(0.5 * (double)N); if (k < 1) k = 1;
  const int nblk_e = (E + EBLK - 1) / EBLK;
  const int NR = (N + HR - 1) / HR;                  // histogram ranges (4 @ N=200k)

  char* w = (char*)d_ws;
  size_t off = 0;
  auto alloc = [&](size_t bytes)->char*{
    char* p = w + off;
    off = (off + bytes + 255) & ~(size_t)255;
    return p;
  };
  float*  s32    = (float*) alloc((size_t)N*4);
  u64*    keysrc = (u64*)   alloc((size_t)N*8);
  u64*    keyS   = (u64*)   alloc((size_t)N*8);
  int*    deg    = (int*)   alloc((size_t)N*4);
  int*    nmap   = (int*)   alloc((size_t)N*4);
  u32*    kmm    = (u32*)   alloc(2*4);
  u32*    hist   = (u32*)   alloc((size_t)NBUCK*4);
  u32*    boffH  = (u32*)   alloc((size_t)NBUCK*4);
  double* s1b    = (double*)alloc((size_t)D*8);
  float*  s1bf   = (float*) alloc((size_t)D*4);
  double* scal   = (double*)alloc(4*8);
  float*  scalf  = (float*) alloc(4*4);
  u64*    sumsq  = (u64*)   alloc(8);
  u32*    r01    = (u32*)   alloc(2*4);
  int*    tot    = (int*)   alloc(4);
  double* bandS  = (double*)alloc((size_t)2*BAND_W*8);
  u16*    wswH   = (u16*)   alloc((size_t)98304*2);
  u16*    wswL   = (u16*)   alloc((size_t)98304*2);
  u16*    wswPH  = (u16*)   alloc((size_t)65536*2);
  int*    bcount = (int*)   alloc((size_t)nblk_e*4);
  int*    boff   = (int*)   alloc((size_t)nblk_e*4);

  float* outX  = (float*)d_out;
  float* outER = outX  + (size_t)k*D;
  float* outEC = outER + (size_t)E;
  float* outS  = outEC + (size_t)E;

  // degree histogram partials in the (not-yet-written) outER/outEC region:
  // NR*HCH*(HR/4)*4 = 12.8 MB << 2*E*4 = 51.2MB, consumed by k_degred2 before edge output.
  u32* partial = (u32*)outER;

  hipMemsetAsync(sumsq,  0,    8,               stream);
  hipMemsetAsync(nmap,   0xFF, (size_t)N*4,     stream);   // = -1
  hipMemsetAsync(kmm,    0xFF, 4,               stream);   // kmin = UINT_MAX
  hipMemsetAsync(kmm+1,  0x00, 4,               stream);   // kmax = 0
  hipMemsetAsync(hist,   0,    (size_t)NBUCK*4, stream);
  hipMemsetAsync(r01,    0xFF, 4,               stream);   // r0 min-init = UINT_MAX
  hipMemsetAsync(r01+1,  0x00, 4,               stream);   // r1 max-init = 0

  k_deghist<<<NR*HCH, 256, 0, stream>>>(ei, E, partial, NR);
  k_degred2<<<1024, 256, 0, stream>>>(partial, N, NR, deg, sumsq);
  k_prep_wsw<<<641, 256, 0, stream>>>(wS1, wF1, wP, alpha, beta, sumsq,
                                      wswH, wswL, wswPH,
                                      s1b, scal, s1bf, scalf);
  k_scores_mfma<<<(N + 63)/64, 512, 0, stream>>>(x, deg, wswH, wswL,
                                                 bS1, wS2, bS2, bF1, wF2, bF2,
                                                 s1bf, scalf, s32, keysrc, kmm, N);

  // counting sort (bucket-granular rank order; exact set pinned by f64 band below)
  k_hist   <<<(N+255)/256, 256, 0, stream>>>(keysrc, N, kmm, hist);
  k_scan64k<<<1, 1024, 0, stream>>>(hist, boffH);
  k_scatter<<<(N+255)/256, 256, 0, stream>>>(keysrc, N, kmm, boffH, keyS);

  // f64 band refinement around the cutoff (cut computation fused into rescore)
  kr_rescore <<<2*BAND_W, 256, 0, stream>>>(keyS, s32, x, deg, wS1,bS1,wS2,bS2,
                                            wF1,bF1,wF2,bF2, s1b, scal,
                                            r01, bandS, k, N);
  kr_bandsort<<<1, 1024, 0, stream>>>(keyS, bandS, r01, k);

  k_xpool_mfma<<<(k+63)/64, 512, 0, stream>>>(x, keyS, wswPH, bP,
                                              s32, nmap, outS, outX, k);
  k_ecount  <<<nblk_e, 256, 0, stream>>>(ei, ei+E, nmap, E, bcount);
  k_escan   <<<1, 1024, 0, stream>>>(bcount, nblk_e, boff, tot);
  k_efill_tail<<<1024, 256, 0, stream>>>(outER, outEC, tot, E);
  k_escatter<<<nblk_e, 256, 0, stream>>>(ei, ei+E, nmap, E, boff, outER, outEC);
}

// Round 18
// 678.945 us; speedup vs baseline: 2.4885x; 2.4885x over previous
//
#include <hip/hip_runtime.h>
#include <math.h>

typedef unsigned long long u64;
typedef unsigned int u32;
typedef unsigned short u16;
typedef __attribute__((ext_vector_type(8))) short bf16x8;
typedef __attribute__((ext_vector_type(4))) float f32x4;

#define D   256
#define ECH 16          // edges per thread
#define EBLK (256*ECH)  // edges per block
#define BAND_W 2048     // rank window half-width around k for f64 refinement
#define BAND_DELTA 1e-3f
#define HR  100352      // histogram nodes per range (25088 u32 words, u8-packed, 100KB LDS)
#define HCH 128         // edge chunks (blocks per range)
#define NBUCK 65536

__device__ __forceinline__ double lrelu(double v){ return v > 0.0 ? v : 0.2*v; }
__device__ __forceinline__ float  lreluf(float v){ return v > 0.0f ? v : 0.2f*v; }

__device__ __forceinline__ u16 f2bf(float f){
  union{float f; u32 u;} v; v.f = f;
  u32 r = v.u + 0x7FFFu + ((v.u >> 16) & 1u);   // RNE
  return (u16)(r >> 16);
}
__device__ __forceinline__ float bf2f(u16 b){
  union{u32 u; float f;} v; v.u = ((u32)b) << 16; return v.f;
}

// ---------------- degree: partitioned LDS histogram, packed u8 counters -------------
__global__ __launch_bounds__(256) void k_deghist(const int* __restrict__ row, int E,
                                                 u32* __restrict__ partial, int NR){
  __shared__ u32 h[HR/4];
  const int tid = threadIdx.x;
  const int r = blockIdx.x % NR;
  const int c = blockIdx.x / NR;
  for (int i = tid; i < HR/4; i += 256) h[i] = 0;
  __syncthreads();
  const int lo = r * HR;
  int CE = ((E + HCH - 1) / HCH + 3) & ~3;      // chunk size, multiple of 4
  const int e0 = c * CE;
  const int e1 = min(e0 + CE, E);
  for (int e = e0 + tid*4; e < e1; e += 256*4){
    if (e + 3 < e1){
      int4 v = *(const int4*)(row + e);
      u32 d0 = (u32)(v.x - lo), d1 = (u32)(v.y - lo);
      u32 d2 = (u32)(v.z - lo), d3 = (u32)(v.w - lo);
      if (d0 < (u32)HR) atomicAdd(&h[d0 >> 2], 1u << ((d0 & 3)*8));
      if (d1 < (u32)HR) atomicAdd(&h[d1 >> 2], 1u << ((d1 & 3)*8));
      if (d2 < (u32)HR) atomicAdd(&h[d2 >> 2], 1u << ((d2 & 3)*8));
      if (d3 < (u32)HR) atomicAdd(&h[d3 >> 2], 1u << ((d3 & 3)*8));
    } else {
      for (int j = 0; j < 4 && e + j < e1; ++j){
        u32 d = (u32)(row[e+j] - lo);
        if (d < (u32)HR) atomicAdd(&h[d >> 2], 1u << ((d & 3)*8));
      }
    }
  }
  __syncthreads();
  u32* plane = partial + (size_t)blockIdx.x * (HR/4);
  for (int i = tid; i < HR/4; i += 256) plane[i] = h[i];
}

__global__ void k_degred2(const u32* __restrict__ partial, int N, int NR,
                          int* __restrict__ deg, u64* __restrict__ out){
  __shared__ u64 sh[256];
  u64 local = 0;
  int stride = gridDim.x*blockDim.x;
  for (int i = blockIdx.x*blockDim.x + threadIdx.x; i < N; i += stride){
    int r = i / HR, off = i % HR;
    const int word = off >> 2, shift = (off & 3)*8;
    u32 s = 0;
    #pragma unroll 8
    for (int c = 0; c < HCH; ++c)
      s += (partial[(size_t)(c*NR + r)*(HR/4) + word] >> shift) & 0xFFu;
    deg[i] = (int)s;
    local += (u64)s * (u64)s;
  }
  sh[threadIdx.x] = local; __syncthreads();
  for (int s = 128; s > 0; s >>= 1){
    if (threadIdx.x < s) sh[threadIdx.x] += sh[threadIdx.x+s];
    __syncthreads();
  }
  if (threadIdx.x == 0) atomicAdd(out, sh[0]);
}

// ---------------- fused prep + weight pre-swizzle ----------------
__global__ void k_prep_wsw(const float* __restrict__ wS1, const float* __restrict__ wF1,
                           const float* __restrict__ wP,
                           const float* __restrict__ alpha, const float* __restrict__ beta,
                           const u64* __restrict__ sumsq,
                           u16* __restrict__ wswH, u16* __restrict__ wswL,
                           u16* __restrict__ wPH,
                           double* __restrict__ s1b, double* __restrict__ scal,
                           float* __restrict__ s1bf, float* __restrict__ scalf){
  const int b = blockIdx.x;
  if (b < 384){
    int idx = b*256 + threadIdx.x;              // 24*8*64*8 = 98304
    int i    = idx & 7;
    int lane = (idx >> 3) & 63;
    int sg   = (idx >> 9) & 7;
    int t    = idx >> 12;
    int k = sg*32 + ((lane >> 4) & 3)*8 + i;
    int c16 = lane & 15;
    float wv;
    if (t < 16) wv = wS1[k*256 + t*16 + c16];
    else        wv = wF1[k*128 + (t-16)*16 + c16];
    u16 h = f2bf(wv);
    wswH[idx] = h;
    wswL[idx] = f2bf(wv - bf2f(h));
  } else if (b < 640){
    int idx = (b-384)*256 + threadIdx.x;        // 16*8*64*8 = 65536
    int i    = idx & 7;
    int lane = (idx >> 3) & 63;
    int sg   = (idx >> 9) & 7;
    int t    = idx >> 12;
    int k = sg*32 + ((lane >> 4) & 3)*8 + i;
    wPH[idx] = f2bf(wP[k*256 + t*16 + (lane & 15)]);
  } else {
    int j = threadIdx.x;
    double s = 0.0;
    for (int r = 0; r < D; ++r) s += (double)wS1[(D + r)*D + j];
    s1b[j] = s;
    s1bf[j] = (float)s;
    if (j == 0){
      double a = 1.0/(1.0 + exp(-(double)alpha[0]));
      double bb = 1.0/(1.0 + exp(-(double)beta[0]));
      scal[0] = a/(a+bb);
      scal[1] = bb/(a+bb);
      double dn = sqrt((double)(*sumsq));
      scal[2] = dn > 1e-12 ? dn : 1e-12;
      scalf[0] = (float)scal[0];
      scalf[1] = (float)scal[1];
      scalf[2] = (float)(1.0/scal[2]);
    }
  }
}

// ---------------- scores via split-bf16 MFMA (frozen structure, lean epilogue) ------
__global__ __launch_bounds__(512, 4) void k_scores_mfma(
    const float* __restrict__ x, const int* __restrict__ deg,
    const u16* __restrict__ wswH, const u16* __restrict__ wswL,
    const float* __restrict__ bS1, const float* __restrict__ wS2, const float* __restrict__ bS2,
    const float* __restrict__ bF1, const float* __restrict__ wF2, const float* __restrict__ bF2,
    const float* __restrict__ s1bf, const float* __restrict__ scalf,
    float* __restrict__ s32, u64* __restrict__ keysrc, u32* __restrict__ kmm, int N)
{
  __shared__ u16 xsh[2][4096];
  __shared__ u16 xsl[2][4096];
  __shared__ float dnsh[64];
  __shared__ float part_s[64][9];
  __shared__ float part_f[64][9];

  const int tid  = threadIdx.x;
  const int lane = tid & 63;
  const int w    = tid >> 6;
  const int node0 = blockIdx.x * 64;

  if (tid < 64){
    int node = node0 + tid;
    dnsh[tid] = (node < N) ? ((float)deg[node] * scalf[2]) : 0.0f;
  }

  const int row_st = tid >> 3;
  const int seg_st = tid & 7;
  const int unit_w = row_st*8 + (seg_st ^ (row_st & 7));
  const float* srcbase = x + (size_t)(node0 + row_st)*D + seg_st*8;
  const bool rv = (node0 + row_st) < N;

  f32x4 acc[4][3];
  #pragma unroll
  for (int m = 0; m < 4; ++m)
    #pragma unroll
    for (int n = 0; n < 3; ++n) acc[m][n] = (f32x4){0.f,0.f,0.f,0.f};

  float xr[8];
  {
    if (rv){
      float4 a = *(const float4*)(srcbase);
      float4 b = *(const float4*)(srcbase + 4);
      xr[0]=a.x; xr[1]=a.y; xr[2]=a.z; xr[3]=a.w;
      xr[4]=b.x; xr[5]=b.y; xr[6]=b.z; xr[7]=b.w;
    } else {
      #pragma unroll
      for (int i = 0; i < 8; ++i) xr[i] = 0.f;
    }
  }

  #pragma unroll
  for (int c = 0; c < 4; ++c){
    const int pb = c & 1;
    {
      u16 h[8];
      #pragma unroll
      for (int i = 0; i < 8; ++i) h[i] = f2bf(xr[i]);
      uint4 H; H.x = (u32)h[0] | ((u32)h[1]<<16); H.y = (u32)h[2] | ((u32)h[3]<<16);
               H.z = (u32)h[4] | ((u32)h[5]<<16); H.w = (u32)h[6] | ((u32)h[7]<<16);
      u16 l[8];
      #pragma unroll
      for (int i = 0; i < 8; ++i) l[i] = f2bf(xr[i] - bf2f(h[i]));
      uint4 L; L.x = (u32)l[0] | ((u32)l[1]<<16); L.y = (u32)l[2] | ((u32)l[3]<<16);
               L.z = (u32)l[4] | ((u32)l[5]<<16); L.w = (u32)l[6] | ((u32)l[7]<<16);
      *(uint4*)&xsh[pb][unit_w*8] = H;
      *(uint4*)&xsl[pb][unit_w*8] = L;
    }
    __syncthreads();
    if (c < 3){
      const float* sn = srcbase + (c+1)*64;
      if (rv){
        float4 a = *(const float4*)(sn);
        float4 b = *(const float4*)(sn + 4);
        xr[0]=a.x; xr[1]=a.y; xr[2]=a.z; xr[3]=a.w;
        xr[4]=b.x; xr[5]=b.y; xr[6]=b.z; xr[7]=b.w;
      }
    }
    #pragma unroll
    for (int s = 0; s < 2; ++s){
      const int sg = c*2 + s;
      bf16x8 ah[4], al[4];
      #pragma unroll
      for (int mt = 0; mt < 4; ++mt){
        int row = mt*16 + (lane & 15);
        int seg = s*4 + (lane >> 4);
        int un  = row*8 + (seg ^ (row & 7));
        ah[mt] = *(const bf16x8*)&xsh[pb][un*8];
        al[mt] = *(const bf16x8*)&xsl[pb][un*8];
      }
      const int t0 = w*3;
      size_t o0 = ((size_t)(t0*8 + sg)*64 + lane)*8;
      bf16x8 bh = *(const bf16x8*)&wswH[o0];
      bf16x8 bl = *(const bf16x8*)&wswL[o0];
      #pragma unroll
      for (int nt = 0; nt < 3; ++nt){
        bf16x8 nbh = bh, nbl = bl;
        if (nt < 2){
          size_t on = ((size_t)((t0+nt+1)*8 + sg)*64 + lane)*8;
          nbh = *(const bf16x8*)&wswH[on];
          nbl = *(const bf16x8*)&wswL[on];
        }
        #pragma unroll
        for (int mt = 0; mt < 4; ++mt){
          acc[mt][nt] = __builtin_amdgcn_mfma_f32_16x16x32_bf16(ah[mt], bh, acc[mt][nt], 0,0,0);
          acc[mt][nt] = __builtin_amdgcn_mfma_f32_16x16x32_bf16(al[mt], bh, acc[mt][nt], 0,0,0);
          acc[mt][nt] = __builtin_amdgcn_mfma_f32_16x16x32_bf16(ah[mt], bl, acc[mt][nt], 0,0,0);
        }
        bh = nbh; bl = nbl;
      }
    }
    if (c < 3) __syncthreads();
  }

  // epilogue: accumulate over nt first, then one 16-lane shuffle reduction per array
  const int c16 = lane & 15;
  float dnl[4][4];
  #pragma unroll
  for (int mt = 0; mt < 4; ++mt)
    #pragma unroll
    for (int j = 0; j < 4; ++j)
      dnl[mt][j] = dnsh[mt*16 + (lane>>4)*4 + j];

  float psv[4][4], pfv[4][4];
  #pragma unroll
  for (int mt = 0; mt < 4; ++mt)
    #pragma unroll
    for (int j = 0; j < 4; ++j){ psv[mt][j] = 0.f; pfv[mt][j] = 0.f; }

  #pragma unroll
  for (int nt = 0; nt < 3; ++nt){
    const int t = w*3 + nt;
    const bool isS = (t < 16);
    const int col = isS ? t*16 + c16 : (t-16)*16 + c16;
    const float bias = isS ? bS1[col] : bF1[col];
    const float sbv  = isS ? s1bf[col] : 0.f;
    const float vv   = isS ? wS2[col] : wF2[col];
    #pragma unroll
    for (int mt = 0; mt < 4; ++mt){
      #pragma unroll
      for (int j = 0; j < 4; ++j){
        float v = acc[mt][nt][j] + bias + dnl[mt][j]*sbv;
        v = lreluf(v) * vv;
        if (isS) psv[mt][j] += v; else pfv[mt][j] += v;
      }
    }
  }
  #pragma unroll
  for (int mt = 0; mt < 4; ++mt){
    #pragma unroll
    for (int j = 0; j < 4; ++j){
      float a = psv[mt][j], b = pfv[mt][j];
      a += __shfl_xor(a, 1); b += __shfl_xor(b, 1);
      a += __shfl_xor(a, 2); b += __shfl_xor(b, 2);
      a += __shfl_xor(a, 4); b += __shfl_xor(b, 4);
      a += __shfl_xor(a, 8); b += __shfl_xor(b, 8);
      if (c16 == 0){
        int row = mt*16 + (lane>>4)*4 + j;
        part_s[row][w] = a;
        part_f[row][w] = b;
      }
    }
  }
  __syncthreads();
  if (tid < 64){
    int node = node0 + tid;
    u32 key32mn = 0xFFFFFFFFu, key32mx = 0u;
    if (node < N){
      float sv = 0.f, fv = 0.f;
      #pragma unroll
      for (int ww = 0; ww < 8; ++ww){ sv += part_s[tid][ww]; fv += part_f[tid][ww]; }
      float sc = scalf[0]*(sv + bS2[0]) + scalf[1]*(fv + bF2[0]);
      s32[node] = sc;
      u32 bits = __float_as_uint(sc);
      u32 ord = (bits >> 31) ? ~bits : (bits | 0x80000000u);
      u32 key32 = ~ord;
      keysrc[node] = ((u64)key32 << 32) | (u32)node;
      key32mn = key32; key32mx = key32;
    }
    #pragma unroll
    for (int off = 32; off > 0; off >>= 1){
      u32 on = __shfl_xor(key32mn, off);
      u32 ox = __shfl_xor(key32mx, off);
      key32mn = min(key32mn, on);
      key32mx = max(key32mx, ox);
    }
    if (tid == 0){
      atomicMin(&kmm[0], key32mn);
      atomicMax(&kmm[1], key32mx);
    }
  }
}

// ---------------- counting sort: hist -> scan -> scatter ----------------
__global__ void k_hist(const u64* __restrict__ keysrc, int N,
                       const u32* __restrict__ kmm, u32* __restrict__ hist){
  const u32 kmin = kmm[0];
  const u64 rng = (u64)(kmm[1] - kmm[0]) + 1;
  int stride = gridDim.x*blockDim.x;
  for (int i = blockIdx.x*blockDim.x + threadIdx.x; i < N; i += stride){
    u32 key = (u32)(keysrc[i] >> 32);
    u32 b = (u32)((((u64)(key - kmin)) << 16) / rng);
    atomicAdd(&hist[b], 1u);
  }
}

__global__ __launch_bounds__(1024) void k_scan64k(const u32* __restrict__ hist,
                                                  u32* __restrict__ boff){
  __shared__ u32 ts[1024];
  const int t = threadIdx.x;
  u32 loc[64];
  u32 s = 0;
  const uint4* hp = (const uint4*)(hist + t*64);
  #pragma unroll
  for (int i = 0; i < 16; ++i){
    uint4 v = hp[i];
    loc[i*4+0]=v.x; loc[i*4+1]=v.y; loc[i*4+2]=v.z; loc[i*4+3]=v.w;
    s += v.x + v.y + v.z + v.w;
  }
  ts[t] = s; __syncthreads();
  for (int d = 1; d < 1024; d <<= 1){
    u32 v = (t >= d) ? ts[t-d] : 0;
    __syncthreads();
    ts[t] += v;
    __syncthreads();
  }
  u32 run = ts[t] - s;
  u32* bp = boff + t*64;
  #pragma unroll 8
  for (int i = 0; i < 64; ++i){ bp[i] = run; run += loc[i]; }
}

__global__ void k_scatter(const u64* __restrict__ keysrc, int N,
                          const u32* __restrict__ kmm, u32* __restrict__ boff,
                          u64* __restrict__ keyS){
  const u32 kmin = kmm[0];
  const u64 rng = (u64)(kmm[1] - kmm[0]) + 1;
  int stride = gridDim.x*blockDim.x;
  for (int i = blockIdx.x*blockDim.x + threadIdx.x; i < N; i += stride){
    u64 kv = keysrc[i];
    u32 key = (u32)(kv >> 32);
    u32 b = (u32)((((u64)(key - kmin)) << 16) / rng);
    u32 pos = atomicAdd(&boff[b], 1u);
    keyS[pos] = kv;
  }
}

// ---------------- f64 band refinement around rank-k cutoff (cut fused in) -----------
__global__ __launch_bounds__(256) void kr_rescore(
    const u64* __restrict__ keys, const float* __restrict__ s32,
    const float* __restrict__ x, const int* __restrict__ deg,
    const float* __restrict__ wS1, const float* __restrict__ bS1,
    const float* __restrict__ wS2, const float* __restrict__ bS2,
    const float* __restrict__ wF1, const float* __restrict__ bF1,
    const float* __restrict__ wF2, const float* __restrict__ bF2,
    const double* __restrict__ s1b, const double* __restrict__ scal,
    u32* __restrict__ r01, double* __restrict__ bandS, int k, int N)
{
  const int r = k - BAND_W + blockIdx.x;
  if (r < 0 || r >= N) return;
  u32 kk32 = (u32)(keys[k-1] >> 32);
  u32 kord = ~kk32;
  u32 ku = (kord & 0x80000000u) ? (kord ^ 0x80000000u) : ~kord;
  const float ccut = __uint_as_float(ku);
  const int node = (int)(u32)(keys[r] & 0xFFFFFFFFULL);
  const float s = s32[node];
  if (s < ccut - BAND_DELTA || s > ccut + BAND_DELTA){
    if (threadIdx.x == 0) bandS[blockIdx.x] = (double)s;
    return;
  }

  const int tid = threadIdx.x;
  if (tid == 0){ atomicMin(&r01[0], (u32)r); atomicMax(&r01[1], (u32)r); }

  __shared__ float xr[256];
  __shared__ double rsp[4], rfp[4];
  xr[tid] = x[(size_t)node*D + tid];
  __syncthreads();

  const int j = tid;
  double a0=0.0, a1=0.0, a2=0.0, a3=0.0;
  double b0=0.0, b1=0.0, b2=0.0, b3=0.0;
  if (j < 128){
    for (int rr = 0; rr < D; rr += 4){
      double x0 = (double)xr[rr+0], x1 = (double)xr[rr+1];
      double x2 = (double)xr[rr+2], x3 = (double)xr[rr+3];
      a0 = fma(x0, (double)wS1[(rr+0)*D + j], a0);
      a1 = fma(x1, (double)wS1[(rr+1)*D + j], a1);
      a2 = fma(x2, (double)wS1[(rr+2)*D + j], a2);
      a3 = fma(x3, (double)wS1[(rr+3)*D + j], a3);
      b0 = fma(x0, (double)wF1[(rr+0)*128 + j], b0);
      b1 = fma(x1, (double)wF1[(rr+1)*128 + j], b1);
      b2 = fma(x2, (double)wF1[(rr+2)*128 + j], b2);
      b3 = fma(x3, (double)wF1[(rr+3)*128 + j], b3);
    }
  } else {
    for (int rr = 0; rr < D; rr += 4){
      double x0 = (double)xr[rr+0], x1 = (double)xr[rr+1];
      double x2 = (double)xr[rr+2], x3 = (double)xr[rr+3];
      a0 = fma(x0, (double)wS1[(rr+0)*D + j], a0);
      a1 = fma(x1, (double)wS1[(rr+1)*D + j], a1);
      a2 = fma(x2, (double)wS1[(rr+2)*D + j], a2);
      a3 = fma(x3, (double)wS1[(rr+3)*D + j], a3);
    }
  }
  double accA = ((a0+a1)+(a2+a3)) + (double)bS1[j] + ((double)deg[node]/scal[2]) * s1b[j];
  double sp = lrelu(accA) * (double)wS2[j];
  double fp = 0.0;
  if (j < 128){
    double accB = ((b0+b1)+(b2+b3)) + (double)bF1[j];
    fp = lrelu(accB) * (double)wF2[j];
  }

  const int lane = tid & 63, wave = tid >> 6;
  #pragma unroll
  for (int off = 32; off > 0; off >>= 1){
    sp += __shfl_down(sp, off);
    fp += __shfl_down(fp, off);
  }
  if (lane == 0){ rsp[wave] = sp; rfp[wave] = fp; }
  __syncthreads();
  if (tid == 0){
    double SP = rsp[0]+rsp[1]+rsp[2]+rsp[3];
    double FP = rfp[0]+rfp[1]+rfp[2]+rfp[3];
    bandS[blockIdx.x] = scal[0]*(SP + (double)bS2[0]) + scal[1]*(FP + (double)bF2[0]);
  }
}

__global__ __launch_bounds__(1024) void kr_bandsort(u64* __restrict__ keys,
    const double* __restrict__ bandS, const u32* __restrict__ r01, int k){
  __shared__ double bs[4096];
  __shared__ int bi[4096];
  if (r01[0] == 0xFFFFFFFFu) return;     // empty band
  const int r0 = (int)r01[0], r1 = (int)r01[1];
  int nb = r1 - r0 + 1;
  if (nb <= 1) return;
  if (nb > 4096) nb = 4096;
  int M = 1; while (M < nb) M <<= 1;
  const int tid = threadIdx.x;
  const int sbase = r0 - (k - BAND_W);
  for (int m = tid; m < M; m += 1024){
    if (m < nb){ bs[m] = bandS[sbase + m]; bi[m] = (int)(u32)(keys[r0+m] & 0xFFFFFFFFULL); }
    else       { bs[m] = -1.0/0.0;         bi[m] = 0x7FFFFFFF; }
  }
  __syncthreads();
  for (int size = 2; size <= M; size <<= 1){
    for (int stride = size >> 1; stride > 0; stride >>= 1){
      for (int p = tid; p < (M >> 1); p += 1024){
        int i = 2*p - (p & (stride-1));
        int jj = i + stride;
        bool up = ((i & size) == 0);
        double si_ = bs[i], sj = bs[jj];
        int ii = bi[i], ij = bi[jj];
        bool gt = (si_ < sj) || (si_ == sj && ii > ij);
        if (gt == up){ bs[i]=sj; bs[jj]=si_; bi[i]=ij; bi[jj]=ii; }
      }
      __syncthreads();
    }
  }
  for (int m = tid; m < nb; m += 1024)
    keys[r0+m] = (u64)(u32)bi[m];
}

// ---------------- x_pooled via pure-bf16 MFMA (finalize fused in) -------------------
__global__ __launch_bounds__(512, 4) void k_xpool_mfma(
    const float* __restrict__ x, const u64* __restrict__ keys,
    const u16* __restrict__ wH, const float* __restrict__ bP,
    const float* __restrict__ s32, int* __restrict__ nmap, float* __restrict__ outS,
    float* __restrict__ out, int kk)
{
  __shared__ u16 xsh[2][4096];

  const int tid  = threadIdx.x;
  const int lane = tid & 63;
  const int w    = tid >> 6;
  const int p0 = blockIdx.x * 64;
  if (p0 >= kk) return;

  // fused k_finalize for this block's 64 ranks
  if (tid < 64){
    int p = p0 + tid;
    if (p < kk){
      int nd = (int)(u32)(keys[p] & 0xFFFFFFFFULL);
      nmap[nd] = p;
      outS[p] = s32[nd];
    }
  }

  const int row_st = tid >> 3;
  const int seg_st = tid & 7;
  const int unit_w = row_st*8 + (seg_st ^ (row_st & 7));
  int prow = p0 + row_st; if (prow >= kk) prow = kk - 1;
  const int node = (int)(u32)(keys[prow] & 0xFFFFFFFFULL);
  const float* srcbase = x + (size_t)node*D + seg_st*8;

  f32x4 acc[4][2];
  #pragma unroll
  for (int m = 0; m < 4; ++m){ acc[m][0] = (f32x4){0.f,0.f,0.f,0.f}; acc[m][1] = (f32x4){0.f,0.f,0.f,0.f}; }

  float xr[8];
  {
    float4 a = *(const float4*)(srcbase);
    float4 b = *(const float4*)(srcbase + 4);
    xr[0]=a.x; xr[1]=a.y; xr[2]=a.z; xr[3]=a.w;
    xr[4]=b.x; xr[5]=b.y; xr[6]=b.z; xr[7]=b.w;
  }

  #pragma unroll
  for (int c = 0; c < 4; ++c){
    const int pb = c & 1;
    {
      u16 h[8];
      #pragma unroll
      for (int i = 0; i < 8; ++i) h[i] = f2bf(xr[i]);
      uint4 H; H.x = (u32)h[0] | ((u32)h[1]<<16); H.y = (u32)h[2] | ((u32)h[3]<<16);
               H.z = (u32)h[4] | ((u32)h[5]<<16); H.w = (u32)h[6] | ((u32)h[7]<<16);
      *(uint4*)&xsh[pb][unit_w*8] = H;
    }
    __syncthreads();
    if (c < 3){
      const float* sn = srcbase + (c+1)*64;
      float4 a = *(const float4*)(sn);
      float4 b = *(const float4*)(sn + 4);
      xr[0]=a.x; xr[1]=a.y; xr[2]=a.z; xr[3]=a.w;
      xr[4]=b.x; xr[5]=b.y; xr[6]=b.z; xr[7]=b.w;
    }
    #pragma unroll
    for (int s = 0; s < 2; ++s){
      const int sg = c*2 + s;
      bf16x8 ah[4];
      #pragma unroll
      for (int mt = 0; mt < 4; ++mt){
        int row = mt*16 + (lane & 15);
        int seg = s*4 + (lane >> 4);
        int un  = row*8 + (seg ^ (row & 7));
        ah[mt] = *(const bf16x8*)&xsh[pb][un*8];
      }
      const int t0 = w*2;
      size_t o0 = ((size_t)(t0*8 + sg)*64 + lane)*8;
      bf16x8 bh = *(const bf16x8*)&wH[o0];
      #pragma unroll
      for (int nt = 0; nt < 2; ++nt){
        bf16x8 nbh = bh;
        if (nt < 1){
          size_t on = ((size_t)((t0+1)*8 + sg)*64 + lane)*8;
          nbh = *(const bf16x8*)&wH[on];
        }
        #pragma unroll
        for (int mt = 0; mt < 4; ++mt)
          acc[mt][nt] = __builtin_amdgcn_mfma_f32_16x16x32_bf16(ah[mt], bh, acc[mt][nt], 0,0,0);
        bh = nbh;
      }
    }
    if (c < 3) __syncthreads();
  }

  const int c16 = lane & 15, r4 = (lane >> 4)*4;
  #pragma unroll
  for (int nt = 0; nt < 2; ++nt){
    const int col = (w*2 + nt)*16 + c16;
    const float bias = bP[col];
    #pragma unroll
    for (int mt = 0; mt < 4; ++mt){
      #pragma unroll
      for (int j = 0; j < 4; ++j){
        int p = p0 + mt*16 + r4 + j;
        if (p < kk) out[(size_t)p*D + col] = lreluf(acc[mt][nt][j] + bias);
      }
    }
  }
}

// ---------------- edge remap + stable compaction (r13-proven 3-kernel) --------------
__global__ __launch_bounds__(256) void k_ecount(const int* __restrict__ erow, const int* __restrict__ ecol,
    const int* __restrict__ nmap, int E, int* __restrict__ bcount){
  __shared__ int sc[256];
  const int tid = threadIdx.x;
  const int base = blockIdx.x*EBLK + tid*ECH;
  int cnt = 0;
  #pragma unroll
  for (int q = 0; q < ECH; ++q){
    int e = base + q;
    if (e < E){
      if (nmap[erow[e]] >= 0 && nmap[ecol[e]] >= 0) cnt++;
    }
  }
  sc[tid] = cnt; __syncthreads();
  for (int s = 128; s > 0; s >>= 1){
    if (tid < s) sc[tid] += sc[tid+s];
    __syncthreads();
  }
  if (tid == 0) bcount[blockIdx.x] = sc[0];
}

__global__ __launch_bounds__(1024) void k_escan(const int* __restrict__ bcount, int nblk,
                                                int* __restrict__ boff, int* __restrict__ tot){
  __shared__ int sh[1024];
  const int tid = threadIdx.x;
  int carry = 0;
  for (int s = 0; s < nblk; s += 1024){
    int v = (s + tid < nblk) ? bcount[s+tid] : 0;
    sh[tid] = v; __syncthreads();
    for (int d = 1; d < 1024; d <<= 1){
      int t = (tid >= d) ? sh[tid-d] : 0;
      __syncthreads();
      sh[tid] += t;
      __syncthreads();
    }
    if (s + tid < nblk) boff[s+tid] = carry + sh[tid] - v;
    carry += sh[1023];
    __syncthreads();
  }
  if (tid == 0) *tot = carry;
}

__global__ void k_efill_tail(float* __restrict__ outR, float* __restrict__ outC,
                             const int* __restrict__ tot, int E){
  const int t0 = *tot;
  int stride = gridDim.x*blockDim.x;
  for (int i = t0 + blockIdx.x*blockDim.x + threadIdx.x; i < E; i += stride){
    outR[i] = -1.0f;
    outC[i] = -1.0f;
  }
}

__global__ __launch_bounds__(256) void k_escatter(const int* __restrict__ erow, const int* __restrict__ ecol,
    const int* __restrict__ nmap, int E, const int* __restrict__ boff,
    float* __restrict__ outR, float* __restrict__ outC){
  __shared__ int sc[256];
  const int tid = threadIdx.x;
  const int base = blockIdx.x*EBLK + tid*ECH;
  int mr[ECH], mc[ECH];
  int cnt = 0;
  #pragma unroll
  for (int q = 0; q < ECH; ++q){
    int e = base + q;
    int a = -1, b = -1;
    if (e < E){ a = nmap[erow[e]]; b = nmap[ecol[e]]; }
    mr[q] = a; mc[q] = b;
    if (a >= 0 && b >= 0) cnt++;
  }
  sc[tid] = cnt; __syncthreads();
  int v = cnt;
  for (int d = 1; d < 256; d <<= 1){
    int t = (tid >= d) ? sc[tid-d] : 0;
    __syncthreads();
    sc[tid] += t;
    __syncthreads();
  }
  int pos = boff[blockIdx.x] + sc[tid] - v;
  #pragma unroll
  for (int q = 0; q < ECH; ++q){
    if (mr[q] >= 0 && mc[q] >= 0){
      outR[pos] = (float)mr[q];
      outC[pos] = (float)mc[q];
      pos++;
    }
  }
}

// ---------------- host ----------------
extern "C" void kernel_launch(void* const* d_in, const int* in_sizes, int n_in,
                              void* d_out, int out_size, void* d_ws, size_t ws_size,
                              hipStream_t stream)
{
  const float* x   = (const float*)d_in[0];
  const int*   ei  = (const int*)d_in[1];
  const float* wS1 = (const float*)d_in[2];
  const float* bS1 = (const float*)d_in[3];
  const float* wS2 = (const float*)d_in[4];
  const float* bS2 = (const float*)d_in[5];
  const float* wF1 = (const float*)d_in[6];
  const float* bF1 = (const float*)d_in[7];
  const float* wF2 = (const float*)d_in[8];
  const float* bF2 = (const float*)d_in[9];
  const float* wP  = (const float*)d_in[10];
  const float* bP  = (const float*)d_in[11];
  const float* alpha = (const float*)d_in[12];
  const float* beta  = (const float*)d_in[13];
  (void)n_in; (void)out_size; (void)ws_size;

  const int N = in_sizes[0] / D;
  const int E = in_sizes[1] / 2;
  int k = (int)(0.5 * (double)N); if (k < 1) k = 1;
  const int nblk_e = (E + EBLK - 1) / EBLK;
  const int NR = (N + HR - 1) / HR;                  // histogram ranges (2 @ N=200k)

  char* w = (char*)d_ws;
  size_t off = 0;
  auto alloc = [&](size_t bytes)->char*{
    char* p = w + off;
    off = (off + bytes + 255) & ~(size_t)255;
    return p;
  };
  float*  s32    = (float*) alloc((size_t)N*4);
  u64*    keysrc = (u64*)   alloc((size_t)N*8);
  u64*    keyS   = (u64*)   alloc((size_t)N*8);
  int*    deg    = (int*)   alloc((size_t)N*4);
  int*    nmap   = (int*)   alloc((size_t)N*4);
  u32*    kmm    = (u32*)   alloc(2*4);
  u32*    hist   = (u32*)   alloc((size_t)NBUCK*4);
  u32*    boffH  = (u32*)   alloc((size_t)NBUCK*4);
  double* s1b    = (double*)alloc((size_t)D*8);
  float*  s1bf   = (float*) alloc((size_t)D*4);
  double* scal   = (double*)alloc(4*8);
  float*  scalf  = (float*) alloc(4*4);
  u64*    sumsq  = (u64*)   alloc(8);
  u32*    r01    = (u32*)   alloc(2*4);
  int*    tot    = (int*)   alloc(4);
  double* bandS  = (double*)alloc((size_t)2*BAND_W*8);
  u16*    wswH   = (u16*)   alloc((size_t)98304*2);
  u16*    wswL   = (u16*)   alloc((size_t)98304*2);
  u16*    wswPH  = (u16*)   alloc((size_t)65536*2);
  int*    bcount = (int*)   alloc((size_t)nblk_e*4);
  int*    boff   = (int*)   alloc((size_t)nblk_e*4);

  float* outX  = (float*)d_out;
  float* outER = outX  + (size_t)k*D;
  float* outEC = outER + (size_t)E;
  float* outS  = outEC + (size_t)E;

  // degree histogram partials in the (not-yet-written) outER/outEC region:
  // NR*HCH*(HR/4)*4 = 25.7 MB << 2*E*4 = 51.2MB, consumed by k_degred2 before edge output.
  u32* partial = (u32*)outER;

  hipMemsetAsync(sumsq,  0,    8,               stream);
  hipMemsetAsync(nmap,   0xFF, (size_t)N*4,     stream);   // = -1
  hipMemsetAsync(kmm,    0xFF, 4,               stream);   // kmin = UINT_MAX
  hipMemsetAsync(kmm+1,  0x00, 4,               stream);   // kmax = 0
  hipMemsetAsync(hist,   0,    (size_t)NBUCK*4, stream);
  hipMemsetAsync(r01,    0xFF, 4,               stream);   // r0 min-init = UINT_MAX
  hipMemsetAsync(r01+1,  0x00, 4,               stream);   // r1 max-init = 0

  k_deghist<<<NR*HCH, 256, 0, stream>>>(ei, E, partial, NR);
  k_degred2<<<1024, 256, 0, stream>>>(partial, N, NR, deg, sumsq);
  k_prep_wsw<<<641, 256, 0, stream>>>(wS1, wF1, wP, alpha, beta, sumsq,
                                      wswH, wswL, wswPH,
                                      s1b, scal, s1bf, scalf);
  k_scores_mfma<<<(N + 63)/64, 512, 0, stream>>>(x, deg, wswH, wswL,
                                                 bS1, wS2, bS2, bF1, wF2, bF2,
                                                 s1bf, scalf, s32, keysrc, kmm, N);

  // counting sort (bucket-granular rank order; exact set pinned by f64 band below)
  k_hist   <<<(N+255)/256, 256, 0, stream>>>(keysrc, N, kmm, hist);
  k_scan64k<<<1, 1024, 0, stream>>>(hist, boffH);
  k_scatter<<<(N+255)/256, 256, 0, stream>>>(keysrc, N, kmm, boffH, keyS);

  // f64 band refinement around the cutoff (cut computation fused into rescore)
  kr_rescore <<<2*BAND_W, 256, 0, stream>>>(keyS, s32, x, deg, wS1,bS1,wS2,bS2,
                                            wF1,bF1,wF2,bF2, s1b, scal,
                                            r01, bandS, k, N);
  kr_bandsort<<<1, 1024, 0, stream>>>(keyS, bandS, r01, k);

  k_xpool_mfma<<<(k+63)/64, 512, 0, stream>>>(x, keyS, wswPH, bP,
                                              s32, nmap, outS, outX, k);
  k_ecount  <<<nblk_e, 256, 0, stream>>>(ei, ei+E, nmap, E, bcount);
  k_escan   <<<1, 1024, 0, stream>>>(bcount, nblk_e, boff, tot);
  k_efill_tail<<<1024, 256, 0, stream>>>(outER, outEC, tot, E);
  k_escatter<<<nblk_e, 256, 0, stream>>>(ei, ei+E, nmap, E, boff, outER, outEC);
}